// Round 1
// baseline (419.258 us; speedup 1.0000x reference)
//
#include <hip/hip_runtime.h>
#include <cstdint>
#include <cstddef>

typedef __attribute__((ext_vector_type(8))) _Float16 half8;
typedef __attribute__((ext_vector_type(4))) float floatx4;

// ---------------- edge dtype detection (int64 vs int32) ----------------
// If edge_index is int64, every odd 32-bit word (high half of a nonnegative
// value < 2^31) is zero. If int32, odd words are real node ids (~0 prob all 0).
__global__ void detect_i64(const int* __restrict__ ei, int npairs, int* __restrict__ is32) {
  int i = blockIdx.x * blockDim.x + threadIdx.x;
  if (i < npairs && ei[2 * i + 1] != 0) atomicOr(is32, 1);
}

// ---------------- fp32 -> fp16 convert (vectorized) ----------------
__global__ void f32_to_f16_k(const float* __restrict__ in, _Float16* __restrict__ out, int n) {
  int i = (blockIdx.x * blockDim.x + threadIdx.x) * 8;
  if (i + 8 <= n) {
    float4 a = *(const float4*)(in + i);
    float4 b = *(const float4*)(in + i + 4);
    half8 v;
    v[0] = (_Float16)a.x; v[1] = (_Float16)a.y; v[2] = (_Float16)a.z; v[3] = (_Float16)a.w;
    v[4] = (_Float16)b.x; v[5] = (_Float16)b.y; v[6] = (_Float16)b.z; v[7] = (_Float16)b.w;
    *(half8*)(out + i) = v;
  } else if (i < n) {
    for (int j = i; j < n; ++j) out[j] = (_Float16)in[j];
  }
}

// ---------------- weight prep: [K][128] fp32 -> [128][K] fp16 (transposed) ----------------
__global__ void prep_w_k(const float* __restrict__ W, _Float16* __restrict__ Wt, int K) {
  int i = blockIdx.x * blockDim.x + threadIdx.x;
  if (i < K * 128) {
    int k = i >> 7, n = i & 127;
    Wt[n * K + k] = (_Float16)W[i];
  }
}

// ---------------- CSR build ----------------
__global__ void hist_k(const int* __restrict__ ei, int E, const int* __restrict__ is32p,
                       int* __restrict__ counts) {
  int e = blockIdx.x * blockDim.x + threadIdx.x;
  if (e >= E) return;
  int is32 = *is32p;
  int dst = is32 ? ei[E + e] : ei[2 * (E + e)];
  atomicAdd(&counts[dst], 1);
}

__global__ void block_sum_k(const int* __restrict__ counts, int* __restrict__ bsums, int n) {
  int base = blockIdx.x * 1024 + threadIdx.x * 4;
  int s = 0;
#pragma unroll
  for (int j = 0; j < 4; ++j) { int idx = base + j; if (idx < n) s += counts[idx]; }
  for (int d = 32; d > 0; d >>= 1) s += __shfl_down(s, d);
  __shared__ int wsum[4];
  if ((threadIdx.x & 63) == 0) wsum[threadIdx.x >> 6] = s;
  __syncthreads();
  if (threadIdx.x == 0) bsums[blockIdx.x] = wsum[0] + wsum[1] + wsum[2] + wsum[3];
}

// exclusive scan of <=64 block sums; also writes offs[n] = total
__global__ void scan_tops_k(const int* __restrict__ bsums, int* __restrict__ boffs, int nb,
                            int* __restrict__ offs, int n) {
  int lane = threadIdx.x;  // 64 threads
  int v = (lane < nb) ? bsums[lane] : 0;
  int sc = v;
  for (int d = 1; d < 64; d <<= 1) { int t = __shfl_up(sc, d); if (lane >= d) sc += t; }
  if (lane < nb) boffs[lane] = sc - v;
  if (lane == 63) offs[n] = sc;
}

__global__ void scan_fin_k(const int* __restrict__ counts, const int* __restrict__ boffs,
                           int* __restrict__ offs, int n) {
  int tid = threadIdx.x;  // 256
  int i0 = blockIdx.x * 1024 + tid * 4;
  int v[4]; int s = 0;
#pragma unroll
  for (int j = 0; j < 4; ++j) { int idx = i0 + j; v[j] = (idx < n) ? counts[idx] : 0; s += v[j]; }
  int lane = tid & 63, w = tid >> 6;
  int sc = s;
  for (int d = 1; d < 64; d <<= 1) { int t = __shfl_up(sc, d); if (lane >= d) sc += t; }
  __shared__ int wsum[4];
  if (lane == 63) wsum[w] = sc;
  __syncthreads();
  int add = 0;
  for (int j = 0; j < w; ++j) add += wsum[j];
  int run = boffs[blockIdx.x] + add + (sc - s);
#pragma unroll
  for (int j = 0; j < 4; ++j) { int idx = i0 + j; if (idx < n) offs[idx] = run; run += v[j]; }
}

__global__ void scatter_k(const int* __restrict__ ei, int E, const int* __restrict__ is32p,
                          int* __restrict__ cursor, int* __restrict__ csr) {
  int e = blockIdx.x * blockDim.x + threadIdx.x;
  if (e >= E) return;
  int is32 = *is32p;
  int src = is32 ? ei[e] : ei[2 * e];
  int dst = is32 ? ei[E + e] : ei[2 * (E + e)];
  int pos = atomicAdd(&cursor[dst], 1);
  csr[pos] = src;
}

// ---------------- dual GEMM: H = A@W (fp16 out), Rout = A@root + bias (fp32 out) ----------------
// A: [M][K] fp16 row-major. Wt/Rt: [128][K] fp16 (transposed weights).
// Block: 256 thr (4 waves), BM=64 rows, full N=128 (x2 matrices), BK=64.
// mfma_f32_16x16x32_f16; A/B frags are contiguous 8-element k-runs (consistent
// k-relabeling on both operands -> valid). C/D: col=lane&15, row=(lane>>4)*4+reg.
template <int K>
__launch_bounds__(256, 2)
__global__ void gemm_dual_k(const _Float16* __restrict__ A, const _Float16* __restrict__ Wt,
                            const _Float16* __restrict__ Rt, const float* __restrict__ bias,
                            _Float16* __restrict__ H, float* __restrict__ Rout, int M) {
  constexpr int LDP = 72;  // pad 64->72 halfs (16B) : row stride 144B -> 2-way banks (free)
  __shared__ _Float16 As[64 * LDP];
  __shared__ _Float16 Bs[128 * LDP];
  __shared__ _Float16 Cs[128 * LDP];
  const int tid = threadIdx.x;
  const int lane = tid & 63;
  const int w = tid >> 6;
  const int m0 = blockIdx.x * 64;
  const int l15 = lane & 15;
  const int hi = lane >> 4;

  floatx4 acc[16];
#pragma unroll
  for (int t = 0; t < 16; ++t) acc[t] = (floatx4)0.f;

  for (int k0 = 0; k0 < K; k0 += 64) {
    __syncthreads();
    // stage A: 64 rows x 64 k = 512 units of 16B
#pragma unroll
    for (int j = 0; j < 2; ++j) {
      int u = tid + 256 * j;
      int row = u >> 3, ks = u & 7;
      int rg = m0 + row; if (rg >= M) rg = M - 1;  // tail clamp; stores masked later
      half8 v = *(const half8*)(A + (size_t)rg * K + k0 + ks * 8);
      *(half8*)&As[row * LDP + ks * 8] = v;
    }
    // stage W / root chunks: 128 rows x 64 k each
#pragma unroll
    for (int j = 0; j < 4; ++j) {
      int u = tid + 256 * j;
      int row = u >> 3, ks = u & 7;
      *(half8*)&Bs[row * LDP + ks * 8] = *(const half8*)(Wt + row * K + k0 + ks * 8);
      *(half8*)&Cs[row * LDP + ks * 8] = *(const half8*)(Rt + row * K + k0 + ks * 8);
    }
    __syncthreads();
#pragma unroll
    for (int kk = 0; kk < 2; ++kk) {
      half8 af = *(const half8*)&As[(w * 16 + l15) * LDP + kk * 32 + hi * 8];
#pragma unroll
      for (int t = 0; t < 16; ++t) {
        const _Float16* bp = (t < 8) ? Bs : Cs;
        half8 bf = *(const half8*)&bp[((t & 7) * 16 + l15) * LDP + kk * 32 + hi * 8];
        acc[t] = __builtin_amdgcn_mfma_f32_16x16x32_f16(af, bf, acc[t], 0, 0, 0);
      }
    }
  }
  const int r0 = hi * 4;
#pragma unroll
  for (int t = 0; t < 16; ++t) {
    int n = (t & 7) * 16 + l15;
#pragma unroll
    for (int j = 0; j < 4; ++j) {
      int row = m0 + w * 16 + r0 + j;
      if (row < M) {
        if (t < 8) H[(size_t)row * 128 + n] = (_Float16)acc[t][j];
        else       Rout[(size_t)row * 128 + n] = acc[t][j] + bias[n];
      }
    }
  }
}

// ---------------- fused aggregate + mean + root + bias(+relu) ----------------
// One block (128 thr) per dst node; thread c owns channel c.
template <bool RELU, typename OutT>
__global__ void agg_combine(const _Float16* __restrict__ Hh, const float* __restrict__ R,
                            const int* __restrict__ offs, const int* __restrict__ csr,
                            OutT* __restrict__ out) {
  int node = blockIdx.x;
  int c = threadIdx.x;
  int beg = offs[node], end = offs[node + 1];
  float acc = 0.f;
  int e = beg;
  for (; e + 2 <= end; e += 2) {
    int s0 = csr[e], s1 = csr[e + 1];
    acc += (float)Hh[(size_t)s0 * 128 + c] + (float)Hh[(size_t)s1 * 128 + c];
  }
  if (e < end) acc += (float)Hh[(size_t)csr[e] * 128 + c];
  float deg = (float)(end - beg);
  float val = acc / fmaxf(deg, 1.f) + R[(size_t)node * 128 + c];
  if (RELU) val = fmaxf(val, 0.f);
  out[(size_t)node * 128 + c] = (OutT)val;
}

// ---------------- launch ----------------
extern "C" void kernel_launch(void* const* d_in, const int* in_sizes, int n_in,
                              void* d_out, int out_size, void* d_ws, size_t ws_size,
                              hipStream_t stream) {
  const float* x     = (const float*)d_in[0];
  const int*   ei    = (const int*)d_in[1];
  const float* W1    = (const float*)d_in[2];
  const float* root1 = (const float*)d_in[3];
  const float* b1    = (const float*)d_in[4];
  const float* W2    = (const float*)d_in[5];
  const float* root2 = (const float*)d_in[6];
  const float* b2    = (const float*)d_in[7];

  const int M = in_sizes[0] / 256;   // 50000
  const int E = in_sizes[1] / 2;     // 800000

  char* p = (char*)d_ws;
  auto alloc = [&](size_t b) { char* r = p; p += (b + 255) & ~(size_t)255; return r; };
  _Float16* Xh  = (_Float16*)alloc((size_t)M * 256 * 2);
  _Float16* W1t = (_Float16*)alloc((size_t)128 * 256 * 2);
  _Float16* R1t = (_Float16*)alloc((size_t)128 * 256 * 2);
  _Float16* W2t = (_Float16*)alloc((size_t)128 * 128 * 2);
  _Float16* R2t = (_Float16*)alloc((size_t)128 * 128 * 2);
  _Float16* Hh  = (_Float16*)alloc((size_t)M * 128 * 2);   // messages (reused both layers)
  float*    Rb  = (float*)alloc((size_t)M * 128 * 4);      // root path (reused)
  _Float16* hh  = (_Float16*)alloc((size_t)M * 128 * 2);   // layer-1 activations
  int* is32   = (int*)alloc(4);
  int* counts = (int*)alloc((size_t)M * 4);
  int* offs   = (int*)alloc(((size_t)M + 1) * 4);
  int* cursor = (int*)alloc((size_t)M * 4);
  int* bsums  = (int*)alloc(64 * 4);
  int* boffs  = (int*)alloc(64 * 4);
  int* csr    = (int*)alloc((size_t)E * 4);

  hipMemsetAsync(is32, 0, 4, stream);
  hipMemsetAsync(counts, 0, (size_t)M * 4, stream);

  detect_i64<<<4, 256, 0, stream>>>(ei, 1024, is32);
  {
    int n = M * 256;
    int g = (n / 8 + 255) / 256;
    f32_to_f16_k<<<g, 256, 0, stream>>>(x, Xh, n);
  }
  prep_w_k<<<128, 256, 0, stream>>>(W1, W1t, 256);
  prep_w_k<<<128, 256, 0, stream>>>(root1, R1t, 256);
  prep_w_k<<<64, 256, 0, stream>>>(W2, W2t, 128);
  prep_w_k<<<64, 256, 0, stream>>>(root2, R2t, 128);

  hist_k<<<(E + 255) / 256, 256, 0, stream>>>(ei, E, is32, counts);
  int nb = (M + 1023) / 1024;  // 49 (<=64 required by scan_tops_k)
  block_sum_k<<<nb, 256, 0, stream>>>(counts, bsums, M);
  scan_tops_k<<<1, 64, 0, stream>>>(bsums, boffs, nb, offs, M);
  scan_fin_k<<<nb, 256, 0, stream>>>(counts, boffs, offs, M);
  hipMemcpyAsync(cursor, offs, (size_t)M * 4, hipMemcpyDeviceToDevice, stream);
  scatter_k<<<(E + 255) / 256, 256, 0, stream>>>(ei, E, is32, cursor, csr);

  int gb = (M + 63) / 64;
  gemm_dual_k<256><<<gb, 256, 0, stream>>>(Xh, W1t, R1t, b1, Hh, Rb, M);
  agg_combine<true, _Float16><<<M, 128, 0, stream>>>(Hh, Rb, offs, csr, hh);
  gemm_dual_k<128><<<gb, 256, 0, stream>>>(hh, W2t, R2t, b2, Hh, Rb, M);
  agg_combine<false, float><<<M, 128, 0, stream>>>(Hh, Rb, offs, csr, (float*)d_out);
}